// Round 17
// baseline (70.512 us; speedup 1.0000x reference)
//
#include <hip/hip_runtime.h>

#define B_SZ   256
#define T_SZ   512
#define EMB    128
#define HID    256
#define NCLS   32000
#define NBLK   250

typedef __attribute__((ext_vector_type(8))) short short8;
typedef __attribute__((ext_vector_type(4))) float f32x4;

__device__ inline unsigned short bf16rne(float f) {
    union { float f; unsigned int u; } v; v.f = f;
    unsigned int u = v.u;
    u += 0x7FFFu + ((u >> 16) & 1u);
    return (unsigned short)(u >> 16);
}
__device__ inline unsigned pkhi(float lo, float hi) {
    union { float f; unsigned u; } a, b;
    a.f = lo; b.f = hi;
    return ((b.u + 0x8000u) & 0xFFFF0000u) | ((a.u + 0x8000u) >> 16);
}
__device__ inline float fsigmoid(float x) { return 1.f / (1.f + __expf(-x)); }
__device__ inline float ftanh(float x)    { return 2.f / (1.f + __expf(-2.f * x)) - 1.f; }

// ---------------------------------------------------------------------------
// SINGLE-DISPATCH fused kernel, NO grid barrier (R8-R15's fusion failures
// were all the producer->consumer handshake; here every block computes the
// whole 256x256 h itself — only 50 MFLOP = 384 gate-MFMAs, hidden under
// the W HBM stream).
//
// 250 blocks x 512 thr, LDS = h 128 KB (frag-major) + E quarter 16 KB.
// Per block:
//   1. issue 16 W dwordx4 -> regs (R7-proven coalescing), HBM starts t=0
//   2. stage E quarter 0 (C_table gather f32 -> bf16 frag-major LDS)
//   3. cvt W -> aw (waits W; E/U L2 reads continue under nothing)
//   4. aU frags: U columns as bf16 A-frags (strided f32 loads, L2-hot)
//   5. 4 m-quarters: gates-GEMM D[k][m] += U^T E (A=U-cols lane=k,
//      B=E-rows lane=m, bias in MFMA C-init) -> sigmoid/tanh (fast exp)
//      -> h scatter ds_write_b32 (pack k-pairs) into frag-major Hs
//   6. __syncthreads; R7-verbatim big GEMM: bh ds_read_b128 (conflict-
//      free), 128 MFMA, bias, f32x4 stores
// h never touches HBM; no second dispatch; no fences.
// ---------------------------------------------------------------------------
__global__ __launch_bounds__(512, 2)
void fused_all(const int* __restrict__ X, const float* __restrict__ C_table,
               const float* __restrict__ U_i, const float* __restrict__ b_i,
               const float* __restrict__ U_c, const float* __restrict__ b_c,
               const float* __restrict__ U_o, const float* __restrict__ b_o,
               const float* __restrict__ Ww, const float* __restrict__ b_out,
               float* __restrict__ out) {
    __shared__ unsigned short Hs[B_SZ * HID];     // 128 KB h, frag-major
    __shared__ unsigned short Ebuf[16 * 512];     // 16 KB: one 64-m quarter

    const int t    = threadIdx.x;
    const int wid  = t >> 6;             // 0..7
    const int lane = t & 63;
    const int l15  = lane & 15;
    const int lq   = lane >> 4;          // 0..3

    const int nbase = blockIdx.x * 128 + wid * 16;

    // ---- 1. W stripe direct to regs ----
    const float* wrow = Ww + (size_t)(nbase + l15) * HID + lq * 8;
    f32x4 wf[16];
    #pragma unroll
    for (int ks = 0; ks < 8; ++ks) {
        wf[2 * ks]     = *reinterpret_cast<const f32x4*>(wrow + ks * 32);
        wf[2 * ks + 1] = *reinterpret_cast<const f32x4*>(wrow + ks * 32 + 4);
    }

    // ---- 2. stage E quarter 0 ----
    // Ebuf frag (mfq,ks): entry ln: m = q*64+mfq*16+(ln&15), e = ks*32+(ln>>4)*8+j
    auto stageE = [&](int q) {
        #pragma unroll
        for (int j2 = 0; j2 < 2; ++j2) {
            const int idx  = j2 * 512 + t;
            const int frag = idx >> 6;          // 0..15 = mfq*4 + ks
            const int ln   = idx & 63;
            const int m    = q * 64 + (frag >> 2) * 16 + (ln & 15);
            const int e0   = (frag & 3) * 32 + (ln >> 4) * 8;
            const int tok  = X[(size_t)m * T_SZ + (T_SZ - 1)];
            const float* ep = C_table + (size_t)tok * EMB + e0;
            f32x4 a = *reinterpret_cast<const f32x4*>(ep);
            f32x4 b = *reinterpret_cast<const f32x4*>(ep + 4);
            union { short8 s; unsigned u[4]; } p;
            p.u[0] = pkhi(a[0], a[1]); p.u[1] = pkhi(a[2], a[3]);
            p.u[2] = pkhi(b[0], b[1]); p.u[3] = pkhi(b[2], b[3]);
            *reinterpret_cast<short8*>(&Ebuf[frag * 512 + ln * 8]) = p.s;
        }
    };
    stageE(0);

    // ---- 3. cvt W -> bf16 A-frags (the wf read waits W; frees 32 VGPR) ----
    short8 aw[8];
    #pragma unroll
    for (int ks = 0; ks < 8; ++ks) {
        union { short8 s; unsigned u[4]; } p;
        p.u[0] = pkhi(wf[2 * ks][0],     wf[2 * ks][1]);
        p.u[1] = pkhi(wf[2 * ks][2],     wf[2 * ks][3]);
        p.u[2] = pkhi(wf[2 * ks + 1][0], wf[2 * ks + 1][1]);
        p.u[3] = pkhi(wf[2 * ks + 1][2], wf[2 * ks + 1][3]);
        aw[ks] = p.s;
    }
    __syncthreads();                     // Ebuf q0 ready

    // ---- 4. aU: U columns as A-frags; k = wid*32 + ss*16 + l15 ----
    short8 aU[3][8];                     // [gate][ss*4+ks], 96 VGPR
    {
        const float* Ug[3] = {U_i, U_c, U_o};
        #pragma unroll
        for (int g = 0; g < 3; ++g)
            #pragma unroll
            for (int ss = 0; ss < 2; ++ss)
                #pragma unroll
                for (int ks = 0; ks < 4; ++ks) {
                    const int kcol = wid * 32 + ss * 16 + l15;
                    const float* up = Ug[g] + (ks * 32 + lq * 8) * HID + kcol;
                    float u8[8];
                    #pragma unroll
                    for (int j = 0; j < 8; ++j) u8[j] = up[j * HID];
                    union { short8 s; unsigned u[4]; } p;
                    p.u[0] = pkhi(u8[0], u8[1]); p.u[1] = pkhi(u8[2], u8[3]);
                    p.u[2] = pkhi(u8[4], u8[5]); p.u[3] = pkhi(u8[6], u8[7]);
                    aU[g][ss * 4 + ks] = p.s;
                }
    }

    // gate biases as MFMA C-init: bgv[g][ss] = b_g[k0 + lq*4 .. +3]
    f32x4 bgv[3][2];
    {
        const float* bg[3] = {b_i, b_c, b_o};
        #pragma unroll
        for (int g = 0; g < 3; ++g)
            #pragma unroll
            for (int ss = 0; ss < 2; ++ss)
                bgv[g][ss] = *reinterpret_cast<const f32x4*>(
                    bg[g] + wid * 32 + ss * 16 + lq * 4);
    }

    // ---- 5. gates + activations + h scatter, 4 m-quarters ----
    #pragma unroll 1
    for (int q = 0; q < 4; ++q) {
        #pragma unroll
        for (int ss = 0; ss < 2; ++ss) {
            f32x4 acc[3][4];             // [gate][mfq]
            #pragma unroll
            for (int g = 0; g < 3; ++g)
                #pragma unroll
                for (int mfq = 0; mfq < 4; ++mfq) acc[g][mfq] = bgv[g][ss];

            #pragma unroll
            for (int ks = 0; ks < 4; ++ks)
                #pragma unroll
                for (int mfq = 0; mfq < 4; ++mfq) {
                    short8 bE = *reinterpret_cast<const short8*>(
                        &Ebuf[(mfq * 4 + ks) * 512 + lane * 8]);
                    #pragma unroll
                    for (int g = 0; g < 3; ++g)
                        acc[g][mfq] = __builtin_amdgcn_mfma_f32_16x16x32_bf16(
                            aU[g][ss * 4 + ks], bE, acc[g][mfq], 0, 0, 0);
                }

            // activations + scatter: k = wid*32 + ss*16 + lq*4 + r
            const int lin = (ss * 2 + (lq >> 1)) * 16 + l15;     // lane_in
            #pragma unroll
            for (int mfq = 0; mfq < 4; ++mfq) {
                const int frag = ((q * 4 + mfq) * 8 + wid);
                float h[4];
                #pragma unroll
                for (int r = 0; r < 4; ++r) {
                    const float i0 = fsigmoid(acc[0][mfq][r]);
                    const float g0 = ftanh(acc[1][mfq][r]);
                    const float o0 = fsigmoid(acc[2][mfq][r]);
                    h[r] = o0 * ftanh(i0 * g0);
                }
                unsigned* dst = reinterpret_cast<unsigned*>(
                    &Hs[frag * 512 + lin * 8 + (lq & 1) * 4]);
                dst[0] = pkhi(h[0], h[1]);
                dst[1] = pkhi(h[2], h[3]);
            }
        }
        __syncthreads();                 // all reads of Ebuf q done
        if (q < 3) {
            stageE(q + 1);
            __syncthreads();             // Ebuf q+1 ready
        }
    }
    __syncthreads();                     // full h in LDS

    // ---- 6. big GEMM: R7-verbatim ----
    f32x4 bv = *reinterpret_cast<const f32x4*>(b_out + nbase + lq * 4);
    const unsigned short* hbase = Hs + lane * 8;
    f32x4 acc[16] = {};
    #pragma unroll
    for (int ks = 0; ks < 8; ++ks) {
        #pragma unroll
        for (int mf = 0; mf < 16; ++mf) {
            short8 bh = *reinterpret_cast<const short8*>(
                hbase + (mf * 8 + ks) * 512);
            acc[mf] = __builtin_amdgcn_mfma_f32_16x16x32_bf16(
                aw[ks], bh, acc[mf], 0, 0, 0);
        }
    }
    #pragma unroll
    for (int mf = 0; mf < 16; ++mf) {
        f32x4 o = acc[mf] + bv;
        *reinterpret_cast<f32x4*>(
            out + (size_t)(mf * 16 + l15) * NCLS + nbase + lq * 4) = o;
    }
}

// ---------------------------------------------------------------------------
extern "C" void kernel_launch(void* const* d_in, const int* in_sizes, int n_in,
                              void* d_out, int out_size, void* d_ws, size_t ws_size,
                              hipStream_t stream) {
    const int*   X       = (const int*)  d_in[0];
    const float* C_table = (const float*)d_in[1];
    const float* U_i     = (const float*)d_in[2];
    const float* b_i     = (const float*)d_in[4];
    const float* U_c     = (const float*)d_in[8];
    const float* b_c     = (const float*)d_in[10];
    const float* U_o     = (const float*)d_in[11];
    const float* b_o     = (const float*)d_in[13];
    const float* W_w     = (const float*)d_in[26];
    const float* b_out   = (const float*)d_in[27];
    float* out = (float*)d_out;

    fused_all<<<NBLK, 512, 0, stream>>>(X, C_table, U_i, b_i, U_c, b_c,
                                        U_o, b_o, W_w, b_out, out);
}

// Round 18
// 33.500 us; speedup vs baseline: 2.1048x; 2.1048x over previous
//
#include <hip/hip_runtime.h>

#define B_SZ   256
#define T_SZ   512
#define EMB    128
#define HID    256
#define NCLS   32000

typedef __attribute__((ext_vector_type(8))) short short8;
typedef __attribute__((ext_vector_type(4))) float f32x4;

__device__ inline unsigned short bf16rne(float f) {
    union { float f; unsigned int u; } v; v.f = f;
    unsigned int u = v.u;
    u += 0x7FFFu + ((u >> 16) & 1u);
    return (unsigned short)(u >> 16);
}
__device__ inline unsigned pkhi(float lo, float hi) {
    union { float f; unsigned u; } a, b;
    a.f = lo; b.f = hi;
    return ((b.u + 0x8000u) & 0xFFFF0000u) | ((a.u + 0x8000u) >> 16);
}

// ---------------------------------------------------------------------------
// h is stored FRAG-MAJOR in d_ws: element (m,k) at
//   frag = (m>>4)*8 + (k>>5); lane = ((k>>3)&3)*16 + (m&15);
//   idx  = frag*512 + lane*8 + (k&7)
// The frags for an m-half (128 rows) are a CONTIGUOUS 64 KB chunk -> LDS
// staging stays linear (rule 21) and ds_read_b128 stays conflict-free.
// ---------------------------------------------------------------------------

// ---------------------------------------------------------------------------
// Kernel 1: VERBATIM R14 lstm (total 27.9 with it; R16 batching was neutral
// so the compiler already pipelines this plain loop).
// ---------------------------------------------------------------------------
__global__ __launch_bounds__(1024)
void lstm_h_last(const int* __restrict__ X, const float* __restrict__ C_table,
                 const float* __restrict__ U_i, const float* __restrict__ b_i,
                 const float* __restrict__ U_c, const float* __restrict__ b_c,
                 const float* __restrict__ U_o, const float* __restrict__ b_o,
                 unsigned short* __restrict__ hws) {
    __shared__ float e[EMB];
    __shared__ float part[3][4][HID];    // 12 KB
    const int m = blockIdx.x;
    const int t = threadIdx.x;           // 0..1023
    const int k = t & 255;               // hidden index
    const int q = t >> 8;                // ee-quarter 0..3

    const int token = X[(size_t)m * T_SZ + (T_SZ - 1)];
    if (t < EMB) e[t] = C_table[(size_t)token * EMB + t];
    __syncthreads();

    float ai = 0.f, ac = 0.f, ao = 0.f;
    const int ee0 = q * 32;
    #pragma unroll
    for (int j = 0; j < 32; ++j) {
        const int ee = ee0 + j;
        const float ev = e[ee];
        ai += ev * U_i[ee * HID + k];
        ac += ev * U_c[ee * HID + k];
        ao += ev * U_o[ee * HID + k];
    }
    part[0][q][k] = ai;
    part[1][q][k] = ac;
    part[2][q][k] = ao;
    __syncthreads();

    if (q == 0) {
        const float si = part[0][0][k] + part[0][1][k] + part[0][2][k] + part[0][3][k];
        const float sc = part[1][0][k] + part[1][1][k] + part[1][2][k] + part[1][3][k];
        const float so = part[2][0][k] + part[2][1][k] + part[2][2][k] + part[2][3][k];
        const float i0 = 1.f / (1.f + expf(-(si + b_i[k])));
        const float g0 = tanhf(sc + b_c[k]);
        const float o0 = 1.f / (1.f + expf(-(so + b_o[k])));
        const unsigned short hv = bf16rne(o0 * tanhf(i0 * g0));
        const int frag = (m >> 4) * 8 + (k >> 5);
        const int li   = ((k >> 3) & 3) * 16 + (m & 15);
        hws[frag * 512 + li * 8 + (k & 7)] = hv;
    }
}

// ---------------------------------------------------------------------------
// Kernel 2 (R18 change): same R7 mechanics, resized for 2 blocks/CU.
// Every prior logits had 128 KB LDS -> 1 block/CU -> chip-synchronized
// phase serialization (HBM idle during h-wait/cvt/MFMA/stores). Now:
// block = 256 thr (4 waves) x [64 n x 128 m(m-half)], Hs = 64 KB ->
// 2 blocks/CU co-resident: one block's stores/compute overlap the other's
// W-loads (m114 cross-block overlap).
// Grid = 1000: bid = nt*2 + mh (mh fastest -> the pair reads the same W
// stripe back-to-back -> second read L3/L2-hit, no HBM duplication).
// Wave: 16-n stripe direct-to-reg W (16 coalesced dwordx4), 8 m-frags from
// LDS (frag-major, conflict-free ds_read_b128), acc[8] = 32 VGPR;
// peak ~130 VGPR << 256 cap at (256,2) -> no spill, 2 blocks resident.
// ---------------------------------------------------------------------------
__global__ __launch_bounds__(256, 2)
void logits_gemm(const unsigned short* __restrict__ hws,
                 const float* __restrict__ Ww,
                 const float* __restrict__ b_out,
                 float* __restrict__ out) {
    __shared__ unsigned short Hs[128 * HID];     // 64 KB: h for this m-half

    const int t    = threadIdx.x;        // 0..255
    const int wid  = t >> 6;             // 0..3
    const int lane = t & 63;
    const int l15  = lane & 15;
    const int lq   = lane >> 4;          // 0..3

    const int mh    = blockIdx.x & 1;            // m-half (fast-varying)
    const int nt    = blockIdx.x >> 1;           // n-tile of 64
    const int nbase = nt * 64 + wid * 16;        // wave's 16-n stripe

    // ---- 1. W stripe direct to regs (HBM long pole starts at t=0) ----
    const float* wrow = Ww + (size_t)(nbase + l15) * HID + lq * 8;
    f32x4 wf[16];
    #pragma unroll
    for (int ks = 0; ks < 8; ++ks) {
        wf[2 * ks]     = *reinterpret_cast<const f32x4*>(wrow + ks * 32);
        wf[2 * ks + 1] = *reinterpret_cast<const f32x4*>(wrow + ks * 32 + 4);
    }

    // ---- 2. stage this m-half's h (contiguous 64 KB, linear, L2-hot) ----
    #pragma unroll
    for (int j = 0; j < 16; ++j) {
        const int lf = wid * 16 + j;             // local frag 0..63
        const unsigned short* src = hws + mh * 32768 + lf * 512 + lane * 8;
        __builtin_amdgcn_global_load_lds(
            (const __attribute__((address_space(1))) unsigned int*)src,
            (__attribute__((address_space(3))) unsigned int*)(Hs + lf * 512),
            16, 0, 0);
    }

    // ---- 3. pin W, drain, barrier ----
    #pragma unroll
    for (int i = 0; i < 16; ++i) asm volatile("" : "+v"(wf[i]));
    asm volatile("s_waitcnt vmcnt(0)" ::: "memory");
    __builtin_amdgcn_s_barrier();
    __builtin_amdgcn_sched_barrier(0);

    // ---- 4. cvt W -> bf16 A-frags ----
    short8 aw[8];
    #pragma unroll
    for (int ks = 0; ks < 8; ++ks) {
        union { short8 s; unsigned u[4]; } p;
        p.u[0] = pkhi(wf[2 * ks][0],     wf[2 * ks][1]);
        p.u[1] = pkhi(wf[2 * ks][2],     wf[2 * ks][3]);
        p.u[2] = pkhi(wf[2 * ks + 1][0], wf[2 * ks + 1][1]);
        p.u[3] = pkhi(wf[2 * ks + 1][2], wf[2 * ks + 1][3]);
        aw[ks] = p.s;
    }

    f32x4 bv = *reinterpret_cast<const f32x4*>(b_out + nbase + lq * 4);

    // ---- 5. MFMA: 8 ks x 8 local m-frags, conflict-free LDS reads ----
    const unsigned short* hbase = Hs + lane * 8;
    f32x4 acc[8] = {};
    #pragma unroll
    for (int ks = 0; ks < 8; ++ks) {
        #pragma unroll
        for (int mf = 0; mf < 8; ++mf) {
            short8 bh = *reinterpret_cast<const short8*>(
                hbase + (mf * 8 + ks) * 512);
            acc[mf] = __builtin_amdgcn_mfma_f32_16x16x32_bf16(
                aw[ks], bh, acc[mf], 0, 0, 0);
        }
    }

    // ---- 6. epilogue: D[n][m] col=l15=m, rows=lq*4+reg -> f32x4 stores ----
    #pragma unroll
    for (int mf = 0; mf < 8; ++mf) {
        const int mg = mh * 128 + mf * 16 + l15;     // global m
        f32x4 o = acc[mf] + bv;
        *reinterpret_cast<f32x4*>(
            out + (size_t)mg * NCLS + nbase + lq * 4) = o;
    }
}

// ---------------------------------------------------------------------------
extern "C" void kernel_launch(void* const* d_in, const int* in_sizes, int n_in,
                              void* d_out, int out_size, void* d_ws, size_t ws_size,
                              hipStream_t stream) {
    const int*   X       = (const int*)  d_in[0];
    const float* C_table = (const float*)d_in[1];
    const float* U_i     = (const float*)d_in[2];
    const float* b_i     = (const float*)d_in[4];
    const float* U_c     = (const float*)d_in[8];
    const float* b_c     = (const float*)d_in[10];
    const float* U_o     = (const float*)d_in[11];
    const float* b_o     = (const float*)d_in[13];
    const float* W_w     = (const float*)d_in[26];
    const float* b_out   = (const float*)d_in[27];
    float* out = (float*)d_out;

    unsigned short* hws = (unsigned short*)d_ws;  // bf16 h_last, frag-major

    lstm_h_last<<<B_SZ, 1024, 0, stream>>>(X, C_table, U_i, b_i, U_c, b_c,
                                           U_o, b_o, hws);
    logits_gemm<<<(NCLS / 64) * 2, 256, 0, stream>>>(hws, W_w, b_out, out);
}

// Round 19
// 28.542 us; speedup vs baseline: 2.4705x; 1.1737x over previous
//
#include <hip/hip_runtime.h>

#define B_SZ   256
#define T_SZ   512
#define EMB    128
#define HID    256
#define NCLS   32000

typedef __attribute__((ext_vector_type(8))) short short8;
typedef __attribute__((ext_vector_type(4))) float f32x4;

__device__ inline unsigned short bf16rne(float f) {
    union { float f; unsigned int u; } v; v.f = f;
    unsigned int u = v.u;
    u += 0x7FFFu + ((u >> 16) & 1u);
    return (unsigned short)(u >> 16);
}
__device__ inline unsigned pkhi(float lo, float hi) {
    union { float f; unsigned u; } a, b;
    a.f = lo; b.f = hi;
    return ((b.u + 0x8000u) & 0xFFFF0000u) | ((a.u + 0x8000u) >> 16);
}

// ---------------------------------------------------------------------------
// h is stored FRAG-MAJOR in d_ws: element (m,k) at
//   frag = (m>>4)*8 + (k>>5); lane = ((k>>3)&3)*16 + (m&15);
//   idx  = frag*512 + lane*8 + (k&7)
// Each B-fragment is a contiguous lane-linear 1 KB block: LDS staging in
// logits is linear (rule 21) and ds_read_b128 is conflict-free (R7-proven).
// ---------------------------------------------------------------------------

// ---------------------------------------------------------------------------
// Kernel 1 (R19 rewrite): h_last for t = T-1 only (layer-0 state never
// updates; layer-1 scan discarded).
// R14/R16 both ran ~19us with SCALAR U loads (96 dword/thread, 1536 VMEM
// instr/CU) — the invariant pig. Now the k-axis is vectorized:
//   lane = k-quad (k = 4*lane+c)  -> float4 U loads, 1KB/wave-instr,
//   wave = 16-e slice, block = 2 m-rows. 12x fewer VMEM instructions,
//   U aggregate 50 MB (128 blocks x 393 KB). 48 independent f32x4 loads
//   per lane (unroll 4 -> ~90 VGPR, no spill at (512,2) cap 128).
// LDS: part[8][3][2][64] f32x4 (48 KB) + e. Waves 0-1 reduce, activate,
// store 8 B per lane into frag-major hws.
// ---------------------------------------------------------------------------
__global__ __launch_bounds__(512, 2)
void lstm_h_last(const int* __restrict__ X, const float* __restrict__ C_table,
                 const float* __restrict__ U_i, const float* __restrict__ b_i,
                 const float* __restrict__ U_c, const float* __restrict__ b_c,
                 const float* __restrict__ U_o, const float* __restrict__ b_o,
                 unsigned short* __restrict__ hws) {
    __shared__ float e[2][EMB];
    __shared__ int   tok[2];
    __shared__ f32x4 part[8][3][2][64];      // 48 KB

    const int t    = threadIdx.x;            // 0..511
    const int wid  = t >> 6;                 // 0..7 = e-group
    const int lane = t & 63;                 // k-quad
    const int m0   = blockIdx.x * 2;
    const int kb   = lane * 4;

    if (t < 2) tok[t] = X[(size_t)(m0 + t) * T_SZ + (T_SZ - 1)];
    __syncthreads();
    if (t < 256) e[t >> 7][t & 127] =
        C_table[(size_t)tok[t >> 7] * EMB + (t & 127)];
    __syncthreads();

    f32x4 acc[3][2] = {};                    // [gate][row]
    #pragma unroll 4
    for (int j = 0; j < 16; ++j) {
        const int ee = wid * 16 + j;
        const f32x4 ui = *reinterpret_cast<const f32x4*>(U_i + (size_t)ee * HID + kb);
        const f32x4 uc = *reinterpret_cast<const f32x4*>(U_c + (size_t)ee * HID + kb);
        const f32x4 uo = *reinterpret_cast<const f32x4*>(U_o + (size_t)ee * HID + kb);
        #pragma unroll
        for (int r = 0; r < 2; ++r) {
            const float ev = e[r][ee];       // LDS broadcast
            acc[0][r] += ev * ui;
            acc[1][r] += ev * uc;
            acc[2][r] += ev * uo;
        }
    }
    #pragma unroll
    for (int g = 0; g < 3; ++g)
        #pragma unroll
        for (int r = 0; r < 2; ++r)
            part[wid][g][r][lane] = acc[g][r];
    __syncthreads();

    if (t < 128) {                           // waves 0-1: reduce + activate
        const int r = wid;                   // 0..1
        const int m = m0 + r;
        f32x4 s[3];
        #pragma unroll
        for (int g = 0; g < 3; ++g) {
            s[g] = part[0][g][r][lane];
            #pragma unroll
            for (int w = 1; w < 8; ++w) s[g] += part[w][g][r][lane];
        }
        const f32x4 bi = *reinterpret_cast<const f32x4*>(b_i + kb);
        const f32x4 bc = *reinterpret_cast<const f32x4*>(b_c + kb);
        const f32x4 bo = *reinterpret_cast<const f32x4*>(b_o + kb);
        float h[4];
        #pragma unroll
        for (int c = 0; c < 4; ++c) {
            const float i0 = 1.f / (1.f + expf(-(s[0][c] + bi[c])));
            const float g0 = tanhf(s[1][c] + bc[c]);
            const float o0 = 1.f / (1.f + expf(-(s[2][c] + bo[c])));
            h[c] = o0 * tanhf(i0 * g0);
        }
        // k = 4*lane + c: frag = (m>>4)*8 + (lane>>3); li = ((lane>>1)&3)*16
        // + (m&15); k&7 = 4*(lane&1)+c -> one aligned 8 B store per lane.
        const int frag = (m >> 4) * 8 + (lane >> 3);
        const int li   = ((lane >> 1) & 3) * 16 + (m & 15);
        unsigned* dst = reinterpret_cast<unsigned*>(
            hws + frag * 512 + li * 8 + (lane & 1) * 4);
        dst[0] = pkhi(h[0], h[1]);
        dst[1] = pkhi(h[2], h[3]);
    }
}

// ---------------------------------------------------------------------------
// Kernel 2: logits[m][n] = sum_k h[m][k]*W[n][k] + b_out[n].  M=256 N=32000
// K=256.  VERBATIM R7/R14 (best total 27.9; R18's 2-block/CU split
// regressed): one-shot, one barrier, W direct to regs (16 fully-coalesced
// dwordx4 per wave = its own 16-row n-stripe), h staged linearly to LDS via
// global_load_lds (frag-major, conflict-free), 128 MFMA, acc[16], stores.
// ---------------------------------------------------------------------------
__global__ __launch_bounds__(512, 2)
void logits_gemm(const unsigned short* __restrict__ hws,
                 const float* __restrict__ Ww,
                 const float* __restrict__ b_out,
                 float* __restrict__ out) {
    __shared__ unsigned short Hs[B_SZ * HID];   // 128 KB, frag-major linear

    const int t    = threadIdx.x;        // 0..511
    const int wid  = t >> 6;             // 0..7
    const int lane = t & 63;
    const int l15  = lane & 15;
    const int lq   = lane >> 4;          // 0..3

    const int nbase = blockIdx.x * 128 + wid * 16;

    // ---- 1. W loads: full K=256 stripe for this lane's n-row ----
    const float* wrow = Ww + (size_t)(nbase + l15) * HID + lq * 8;
    f32x4 wf[16];
    #pragma unroll
    for (int ks = 0; ks < 8; ++ks) {
        wf[2 * ks]     = *reinterpret_cast<const f32x4*>(wrow + ks * 32);
        wf[2 * ks + 1] = *reinterpret_cast<const f32x4*>(wrow + ks * 32 + 4);
    }

    // ---- 2. stage h slice [wid*16KB, +16KB): 16 x 1KB, fully linear ----
    #pragma unroll
    for (int j = 0; j < 16; ++j) {
        const unsigned short* src = hws + (wid * 16 + j) * 512;
        __builtin_amdgcn_global_load_lds(
            (const __attribute__((address_space(1))) unsigned int*)(src + lane * 8),
            (__attribute__((address_space(3))) unsigned int*)(Hs + (wid * 16 + j) * 512),
            16, 0, 0);
    }

    // ---- 3. pin W (forces materialization), drain, barrier ----
    #pragma unroll
    for (int i = 0; i < 16; ++i) asm volatile("" : "+v"(wf[i]));
    asm volatile("s_waitcnt vmcnt(0)" ::: "memory");
    __builtin_amdgcn_s_barrier();
    __builtin_amdgcn_sched_barrier(0);

    // ---- 4. convert W to bf16 A-fragments ----
    short8 aw[8];
    #pragma unroll
    for (int ks = 0; ks < 8; ++ks) {
        union { short8 s; unsigned u[4]; } p;
        p.u[0] = pkhi(wf[2 * ks][0],     wf[2 * ks][1]);
        p.u[1] = pkhi(wf[2 * ks][2],     wf[2 * ks][3]);
        p.u[2] = pkhi(wf[2 * ks + 1][0], wf[2 * ks + 1][1]);
        p.u[3] = pkhi(wf[2 * ks + 1][2], wf[2 * ks + 1][3]);
        aw[ks] = p.s;
    }

    f32x4 bv = *reinterpret_cast<const f32x4*>(b_out + nbase + lq * 4);

    // ---- MFMA: ks-outer -> 16 independent acc chains ----
    const unsigned short* hbase = Hs + lane * 8;
    f32x4 acc[16] = {};
    #pragma unroll
    for (int ks = 0; ks < 8; ++ks) {
        #pragma unroll
        for (int mf = 0; mf < 16; ++mf) {
            short8 bh = *reinterpret_cast<const short8*>(
                hbase + (mf * 8 + ks) * 512);
            acc[mf] = __builtin_amdgcn_mfma_f32_16x16x32_bf16(
                aw[ks], bh, acc[mf], 0, 0, 0);
        }
    }

    // ---- 5. epilogue: bias + stores ----
    #pragma unroll
    for (int mf = 0; mf < 16; ++mf) {
        f32x4 o = acc[mf] + bv;
        *reinterpret_cast<f32x4*>(
            out + (size_t)(mf * 16 + l15) * NCLS + nbase + lq * 4) = o;
    }
}

// ---------------------------------------------------------------------------
extern "C" void kernel_launch(void* const* d_in, const int* in_sizes, int n_in,
                              void* d_out, int out_size, void* d_ws, size_t ws_size,
                              hipStream_t stream) {
    const int*   X       = (const int*)  d_in[0];
    const float* C_table = (const float*)d_in[1];
    const float* U_i     = (const float*)d_in[2];
    const float* b_i     = (const float*)d_in[4];
    const float* U_c     = (const float*)d_in[8];
    const float* b_c     = (const float*)d_in[10];
    const float* U_o     = (const float*)d_in[11];
    const float* b_o     = (const float*)d_in[13];
    const float* W_w     = (const float*)d_in[26];
    const float* b_out   = (const float*)d_in[27];
    float* out = (float*)d_out;

    unsigned short* hws = (unsigned short*)d_ws;  // bf16 h_last, frag-major

    lstm_h_last<<<B_SZ / 2, 512, 0, stream>>>(X, C_table, U_i, b_i, U_c, b_c,
                                              U_o, b_o, hws);
    logits_gemm<<<NCLS / 128, 512, 0, stream>>>(hws, W_w, b_out, out);
}